// Round 2
// baseline (533.439 us; speedup 1.0000x reference)
//
#include <hip/hip_runtime.h>
#include <stdint.h>

#define D 128
#define MT 64

typedef short short8 __attribute__((ext_vector_type(8)));
typedef float f32x16 __attribute__((ext_vector_type(16)));

__device__ __forceinline__ unsigned short f2bf(float f) {
    union { float f; uint32_t u; } v;
    v.f = f;
    uint32_t u = v.u;
    uint32_t r = (u + 0x7fffu + ((u >> 16) & 1u)) >> 16;  // RNE
    return (unsigned short)r;
}

// Pack W1 (384x128) / W2 (128x128) fp32 row-major -> bf16 MFMA-B fragment order:
// frag index ((kt*4 + nt)*64 + lane)*8 + j holds W[k = kt*16 + (lane>>5)*8 + j][n = nt*32 + (lane&31)]
__global__ void pack_weights_kernel(const float* __restrict__ W1,
                                    const float* __restrict__ W2,
                                    unsigned short* __restrict__ W1p,
                                    unsigned short* __restrict__ W2p) {
    int t = blockIdx.x * 256 + threadIdx.x;
    if (t < 6144) {               // W1: 24 ksteps * 4 colblocks * 64 lanes
        int kt = t >> 8, nt = (t >> 6) & 3, lane = t & 63;
        int n = nt * 32 + (lane & 31);
        int kb = kt * 16 + (lane >> 5) * 8;
        unsigned short* dst = W1p + t * 8;
        #pragma unroll
        for (int j = 0; j < 8; ++j) dst[j] = f2bf(W1[(kb + j) * D + n]);
    } else if (t < 8192) {        // W2: 8 ksteps * 4 colblocks * 64 lanes
        int u = t - 6144;
        int kt = u >> 8, nt = (u >> 6) & 3, lane = u & 63;
        int n = nt * 32 + (lane & 31);
        int kb = kt * 16 + (lane >> 5) * 8;
        unsigned short* dst = W2p + u * 8;
        #pragma unroll
        for (int j = 0; j < 8; ++j) dst[j] = f2bf(W2[(kb + j) * D + n]);
    }
}

// 64 edges per block, 512 threads = 8 waves, one 32x32 tile per wave.
// This round: ILP-maximized — batched stage loads (int2 eidx + 12 float4 in flight),
// W1 fragments prefetched depth-4 (first 4 issued before the stage so L2 latency
// hides under the gather), W2 fragments all preloaded before the H-write barrier.
// LDS 50176 B -> 3 blocks/CU = 24 waves/CU; launch_bounds(512,6) caps VGPR at 85.
__global__ __launch_bounds__(512, 6) void edge_mlp_kernel(
    const float* __restrict__ x_node,
    const float* __restrict__ x_edge,
    const int* __restrict__ eidx,
    const unsigned short* __restrict__ W1p,
    const unsigned short* __restrict__ W2p,
    const float* __restrict__ b1,
    const float* __restrict__ b2,
    float* __restrict__ out,
    int E) {
    __shared__ unsigned short lds[MT * 392];   // 50176 B
    unsigned short* Hs = lds;                  // aliased, stride 136 (17*16B)

    const int t = threadIdx.x;
    const int r0 = blockIdx.x * MT;

    const int w = t >> 6;                 // wave id 0..7
    const int cb = w & 3;                 // column block (32 cols)
    const int rt = w >> 2;                // row tile (32 rows)
    const int lane = t & 63;
    const int lrow = lane & 31;
    const int khalf = (lane >> 5) * 8;
    const int n = cb * 32 + lrow;
    const int rbump = (lane >> 5) * 4;
    const int arow = rt * 32 + lrow;

    // Per-wave W fragment base pointers (stride per kstep = 4*64*8 = 2048 shorts)
    const unsigned short* bp1 = W1p + ((size_t)cb * 64 + lane) * 8;
    const unsigned short* bp2 = W2p + ((size_t)cb * 64 + lane) * 8;

    // Early-issue first 4 W1 fragments: L2 latency hides under the gather stage.
    short8 bbuf0 = *(const short8*)(bp1);
    short8 bbuf1 = *(const short8*)(bp1 + 1 * 2048);
    short8 bbuf2 = *(const short8*)(bp1 + 2 * 2048);
    short8 bbuf3 = *(const short8*)(bp1 + 3 * 2048);

    // ---- stage: gather v0|v1|x_edge, convert fp32->bf16, write LDS ----
    {
        const int lane32 = t & 31;
        const int rsub = t >> 5;               // 0..15

        // Batch 1: all edge indices (int2 = both endpoints in one load)
        int2 e[4];
        int rgc[4];
        #pragma unroll
        for (int rb = 0; rb < 4; ++rb) {
            int rg = r0 + rb * 16 + rsub;
            rgc[rb] = rg < E ? rg : E - 1;
            e[rb] = ((const int2*)eidx)[rgc[rb]];
        }
        // Batch 2: all 12 gathers in flight
        float4 v0[4], v1[4], v2[4];
        #pragma unroll
        for (int rb = 0; rb < 4; ++rb) {
            v0[rb] = ((const float4*)(x_node + (size_t)e[rb].x * D))[lane32];
            v1[rb] = ((const float4*)(x_node + (size_t)e[rb].y * D))[lane32];
            v2[rb] = ((const float4*)(x_edge + (size_t)rgc[rb] * D))[lane32];
        }
        // Batch 3: convert + LDS write
        #pragma unroll
        for (int rb = 0; rb < 4; ++rb) {
            int row = rb * 16 + rsub;
            unsigned short* base = &lds[row * 392 + lane32 * 4];
            ushort4 p;
            p.x = f2bf(v0[rb].x); p.y = f2bf(v0[rb].y); p.z = f2bf(v0[rb].z); p.w = f2bf(v0[rb].w);
            *(ushort4*)(base) = p;
            p.x = f2bf(v1[rb].x); p.y = f2bf(v1[rb].y); p.z = f2bf(v1[rb].z); p.w = f2bf(v1[rb].w);
            *(ushort4*)(base + 128) = p;
            p.x = f2bf(v2[rb].x); p.y = f2bf(v2[rb].y); p.z = f2bf(v2[rb].z); p.w = f2bf(v2[rb].w);
            *(ushort4*)(base + 256) = p;
        }
    }
    __syncthreads();

    // ---- GEMM1: H = relu(X_cat @ W1 + b1), K = 384, depth-4 b-prefetch ----
    f32x16 acc;
    #pragma unroll
    for (int i = 0; i < 16; ++i) acc[i] = 0.f;

    #pragma unroll
    for (int kt = 0; kt < 24; ++kt) {
        short8 a = *(const short8*)&lds[arow * 392 + kt * 16 + khalf];
        short8 b;
        switch (kt & 3) {
            case 0: b = bbuf0; if (kt + 4 < 24) bbuf0 = *(const short8*)(bp1 + (kt + 4) * 2048); break;
            case 1: b = bbuf1; if (kt + 4 < 24) bbuf1 = *(const short8*)(bp1 + (kt + 4) * 2048); break;
            case 2: b = bbuf2; if (kt + 4 < 24) bbuf2 = *(const short8*)(bp1 + (kt + 4) * 2048); break;
            default: b = bbuf3; if (kt + 4 < 24) bbuf3 = *(const short8*)(bp1 + (kt + 4) * 2048); break;
        }
        acc = __builtin_amdgcn_mfma_f32_32x32x16_bf16(a, b, acc, 0, 0, 0);
    }

    // Early-issue all 8 W2 fragments: latency hides under epilogue + barrier + H-write.
    short8 b2buf[8];
    #pragma unroll
    for (int i = 0; i < 8; ++i) b2buf[i] = *(const short8*)(bp2 + i * 2048);

    __syncthreads();   // everyone done reading X_cat before H overwrites it

    {
        float b1v = b1[n];
        #pragma unroll
        for (int r = 0; r < 16; ++r) {
            int rr = rt * 32 + (r & 3) + 8 * (r >> 2) + rbump;   // C-layout row
            Hs[rr * 136 + n] = f2bf(fmaxf(acc[r] + b1v, 0.f));
        }
    }
    __syncthreads();

    // ---- GEMM2: OUT = H @ W2 + b2, K = 128, b already in registers ----
    f32x16 c;
    #pragma unroll
    for (int i = 0; i < 16; ++i) c[i] = 0.f;

    #pragma unroll
    for (int kt = 0; kt < 8; ++kt) {
        short8 a = *(const short8*)&Hs[arow * 136 + kt * 16 + khalf];
        c = __builtin_amdgcn_mfma_f32_32x32x16_bf16(a, b2buf[kt], c, 0, 0, 0);
    }

    {
        float b2v = b2[n];
        #pragma unroll
        for (int r = 0; r < 16; ++r) {
            int rr = rt * 32 + (r & 3) + 8 * (r >> 2) + rbump;
            int rg = r0 + rr;
            if (rg < E) out[(size_t)rg * D + n] = c[r] + b2v;
        }
    }
}

extern "C" void kernel_launch(void* const* d_in, const int* in_sizes, int n_in,
                              void* d_out, int out_size, void* d_ws, size_t ws_size,
                              hipStream_t stream) {
    const float* x_node = (const float*)d_in[0];
    const float* x_edge = (const float*)d_in[1];
    const int*   eidx   = (const int*)d_in[2];
    const float* W1     = (const float*)d_in[3];
    const float* b1     = (const float*)d_in[4];
    const float* W2     = (const float*)d_in[5];
    const float* b2     = (const float*)d_in[6];
    float* out = (float*)d_out;

    const int E = in_sizes[1] / D;

    unsigned short* W1p = (unsigned short*)d_ws;          // 6144*8 bf16 = 96 KB
    unsigned short* W2p = W1p + 6144 * 8;                 // 2048*8 bf16 = 32 KB

    pack_weights_kernel<<<32, 256, 0, stream>>>(W1, W2, W1p, W2p);

    int nblk = (E + MT - 1) / MT;
    edge_mlp_kernel<<<nblk, 512, 0, stream>>>(x_node, x_edge, eidx, W1p, W2p, b1, b2, out, E);
}